// Round 1
// 746.824 us; speedup vs baseline: 1.2783x; 1.2783x over previous
//
#include <hip/hip_runtime.h>

#define DIMV 768
#define BATCH 16
#define SEQ 1024
#define LN_EPS 1e-5f

typedef __attribute__((ext_vector_type(8))) short bf16x8;   // 8 bf16 = 4 VGPRs
typedef __attribute__((ext_vector_type(4))) float f32x4;
typedef unsigned short ushort_t;

__device__ __forceinline__ unsigned short f2bf(float f) {
    unsigned u = __float_as_uint(f);
    u = (u + 0x7FFFu + ((u >> 16) & 1u)) >> 16;
    return (unsigned short)u;
}

// ---------------------------------------------------------------------------
// bf16 MFMA NT GEMM, ring-3 LDS pipeline: C[m,n] = scale*sum_k A[m,k]*B[n,k]+bias
// A: bf16 row-major [M, lda]; B: bf16 row-major [N, ldb] (B^T input).
// 128x128 tile, BK=32, 256 threads = 4 waves (2x2), 4x4 MFMA frags/wave.
// K-loop: depth-1 global_load_lds prefetch, ONE raw s_barrier + s_waitcnt
// vmcnt(4) per iter (tile k+1 loads stay in flight across the barrier).
// Ring-3 safety: slot written at iter k was last read at iter k-2; those reads
// precede barrier(k-1), which precedes iter-k issue. Last iter issues a dummy
// wrap prefetch so the vmcnt count stays uniform.
//
// XCD batch-affinity swizzle (z>1 only): hardware round-robins linear block id
// over the 8 XCDs; default mapping gives XCD = blockIdx.x (n-tile), so every
// XCD touches all batches' Q/P panels -> L2 thrash (measured 91 MB fetch vs
// 25 MB compulsory). Remap so XCD == batch (mod 8): one batch's working set
// (<= 3.5 MB) then lives in one XCD's 4 MB L2.
//
// mode: 0 = f32 out; 1 = bf16 out; 2 = bf16 out transposed per-(local)batch
//       (dst[b][n][s], b = m>>10, s = m&1023); 3 = f32 accumulate (C += val).
// ---------------------------------------------------------------------------
__global__ __launch_bounds__(256) void gemm_bf16_nt(
    const ushort_t* __restrict__ A, const ushort_t* __restrict__ B,
    const float* __restrict__ bias, void* __restrict__ Cout,
    int K, int lda, int ldb, int ldc, float scale, int mode,
    long long sAz, long long sBz, long long sCz)
{
    int bx = blockIdx.x, by = blockIdx.y, bz = blockIdx.z;
    {
        const unsigned Z = gridDim.z;
        if (Z > 1) {
            const unsigned nx = gridDim.x, ny = gridDim.y;
            const unsigned nxy = nx * ny;
            const unsigned lid = ((unsigned)bz * ny + (unsigned)by) * nx + (unsigned)bx;
            unsigned r;
            if ((Z & 7u) == 0u) {           // XCD c runs batch c, then c+8, ...
                const unsigned c  = lid & 7u;
                const unsigned rp = lid >> 3;
                bz = (int)(c + 8u * (rp / nxy));
                r  = rp % nxy;
            } else {                        // generic bijective fallback
                bz = (int)(lid % Z);
                r  = lid / Z;
            }
            bx = (int)(r % nx);
            by = (int)(r / nx);
        }
    }

    A += (long long)bz * sAz;
    B += (long long)bz * sBz;
    float*    Cf = (float*)Cout    + ((mode == 0 || mode == 3) ? (long long)bz * sCz : 0);
    ushort_t* Ch = (ushort_t*)Cout + ((mode == 1 || mode == 2) ? (long long)bz * sCz : 0);

    __shared__ ushort_t As[3][128 * 32];   // 3 x 8 KB
    __shared__ ushort_t Bs[3][128 * 32];   // 3 x 8 KB  (48 KB total)

    const int t    = threadIdx.x;       // 0..255
    const int wave = t >> 6;
    const int lane = t & 63;
    const int quad = lane >> 4;         // 0..3
    const int lr   = lane & 15;         // 0..15
    const int wy   = wave >> 1;         // 0/1: m-half
    const int wx   = wave & 1;          // 0/1: n-half

    const int m0 = by * 128;
    const int n0 = bx * 128;

    const ushort_t* Abase = A + (long long)m0 * lda;
    const ushort_t* Bbase = B + (long long)n0 * ldb;

    auto issue = [&](int k0, int slot) {
        #pragma unroll
        for (int i = 0; i < 2; ++i) {
            const int idx = t + 256 * i;          // 0..511: 128 rows x 4 chunks
            const int r   = idx >> 2;
            const int c   = (idx & 3) * 8;        // bf16 offset (16B chunks)
            __builtin_amdgcn_global_load_lds(
                (const __attribute__((address_space(1))) unsigned int*)(Abase + (long long)r * lda + k0 + c),
                (__attribute__((address_space(3))) unsigned int*)&As[slot][idx * 8], 16, 0, 0);
            __builtin_amdgcn_global_load_lds(
                (const __attribute__((address_space(1))) unsigned int*)(Bbase + (long long)r * ldb + k0 + c),
                (__attribute__((address_space(3))) unsigned int*)&Bs[slot][idx * 8], 16, 0, 0);
        }
    };

    f32x4 acc[4][4] = {};

    const int NK = K >> 5;
    issue(0, 0);
    int cur = 0, nxt = 1;
    for (int ki = 0; ki < NK; ++ki) {
        const int kn = (ki + 1 < NK) ? (ki + 1) << 5 : 0;  // dummy wrap on last
        issue(kn, nxt);
        asm volatile("s_waitcnt vmcnt(4)" ::: "memory");   // tile-k loads done
        asm volatile("s_barrier" ::: "memory");            // no vmcnt(0) drain

        const ushort_t* as = &As[cur][0];
        const ushort_t* bs = &Bs[cur][0];
        bf16x8 af[4], bfr[4];
        #pragma unroll
        for (int i = 0; i < 4; ++i) {
            const int row = wy * 64 + i * 16 + lr;      // A[m][k]
            af[i] = *(const bf16x8*)&as[row * 32 + quad * 8];
        }
        #pragma unroll
        for (int j = 0; j < 4; ++j) {
            const int row = wx * 64 + j * 16 + lr;      // B^T[n][k]
            bfr[j] = *(const bf16x8*)&bs[row * 32 + quad * 8];
        }
        #pragma unroll
        for (int i = 0; i < 4; ++i)
            #pragma unroll
            for (int j = 0; j < 4; ++j)
                acc[i][j] = __builtin_amdgcn_mfma_f32_16x16x32_bf16(
                    af[i], bfr[j], acc[i][j], 0, 0, 0);

        cur = nxt;
        nxt = (nxt == 2) ? 0 : nxt + 1;
    }

    // epilogue: D row(m) = quad*4 + reg, col(n) = lane&15  [m89-verified]
    #pragma unroll
    for (int j = 0; j < 4; ++j) {
        const int n = n0 + wx * 64 + j * 16 + lr;
        const float bv = bias ? bias[n] : 0.0f;
        #pragma unroll
        for (int i = 0; i < 4; ++i) {
            #pragma unroll
            for (int r = 0; r < 4; ++r) {
                const int m = m0 + wy * 64 + i * 16 + quad * 4 + r;
                const float val = acc[i][j][r] * scale + bv;
                if (mode == 0) {
                    Cf[(long long)m * ldc + n] = val;
                } else if (mode == 3) {
                    Cf[(long long)m * ldc + n] += val;
                } else if (mode == 1) {
                    Ch[(long long)m * ldc + n] = f2bf(val);
                } else {
                    const int b = m >> 10, s = m & 1023;
                    Ch[(long long)b * (DIMV * SEQ) + (long long)n * SEQ + s] = f2bf(val);
                }
            }
        }
    }
}

// ---------------------------------------------------------------------------
// f32 -> bf16 conversion, 4 elems/thread, count divisible by 1024
// ---------------------------------------------------------------------------
__global__ __launch_bounds__(256) void f32_to_bf16(
    const float* __restrict__ in, ushort_t* __restrict__ out)
{
    const long long i = ((long long)blockIdx.x * 256 + threadIdx.x) * 4;
    float4 v = *reinterpret_cast<const float4*>(in + i);
    ushort4 o;
    o.x = f2bf(v.x); o.y = f2bf(v.y); o.z = f2bf(v.z); o.w = f2bf(v.w);
    *reinterpret_cast<ushort4*>(out + i) = o;
}

// ---------------------------------------------------------------------------
// In-place row softmax: 1024 f32 logits -> bf16 probs written over the row
// start (row becomes 1024 bf16 + 2048B dead). All reads complete before the
// first __syncthreads, so the overlapping writes after the last barrier are
// race-free. One 256-thread block per row.
// ---------------------------------------------------------------------------
__global__ __launch_bounds__(256) void softmax_inplace(float* __restrict__ S)
{
    float* s = S + (long long)blockIdx.x * SEQ;
    const int t = threadIdx.x;
    __shared__ float red[256];

    float4 v = *reinterpret_cast<const float4*>(&s[t * 4]);
    float mx = fmaxf(fmaxf(v.x, v.y), fmaxf(v.z, v.w));
    red[t] = mx;
    __syncthreads();
    for (int st = 128; st > 0; st >>= 1) {
        if (t < st) red[t] = fmaxf(red[t], red[t + st]);
        __syncthreads();
    }
    mx = red[0];
    __syncthreads();

    v.x = __expf(v.x - mx); v.y = __expf(v.y - mx);
    v.z = __expf(v.z - mx); v.w = __expf(v.w - mx);
    red[t] = v.x + v.y + v.z + v.w;
    __syncthreads();
    for (int st = 128; st > 0; st >>= 1) {
        if (t < st) red[t] += red[t + st];
        __syncthreads();
    }
    const float inv = 1.0f / red[0];

    ushort4 o;
    o.x = f2bf(v.x * inv); o.y = f2bf(v.y * inv);
    o.z = f2bf(v.z * inv); o.w = f2bf(v.w * inv);
    *reinterpret_cast<ushort4*>((ushort_t*)s + t * 4) = o;
}

// ---------------------------------------------------------------------------
// h = LayerNorm(ACC + xC) * gamma + beta -> bf16. One block per row (768).
// ---------------------------------------------------------------------------
__global__ __launch_bounds__(256) void add_layernorm(
    const float* __restrict__ ACC, const float* __restrict__ xC,
    const float* __restrict__ gamma, const float* __restrict__ beta,
    ushort_t* __restrict__ H)
{
    const long long row = blockIdx.x;
    const float* a = ACC + row * DIMV;
    const float* x = xC  + row * DIMV;
    ushort_t*    h = H   + row * DIMV;
    const int t = threadIdx.x;

    __shared__ float r1[256];
    __shared__ float r2[256];

    float vals[3];
    float s = 0.f, ss = 0.f;
    #pragma unroll
    for (int i = 0; i < 3; ++i) {
        const int j = t + i * 256;
        float v = a[j] + x[j];
        vals[i] = v;
        s += v; ss += v * v;
    }
    r1[t] = s; r2[t] = ss;
    __syncthreads();
    for (int st = 128; st > 0; st >>= 1) {
        if (t < st) { r1[t] += r1[t + st]; r2[t] += r2[t + st]; }
        __syncthreads();
    }
    const float mu  = r1[0] * (1.0f / DIMV);
    const float var = r2[0] * (1.0f / DIMV) - mu * mu;
    const float inv = rsqrtf(var + LN_EPS);

    #pragma unroll
    for (int i = 0; i < 3; ++i) {
        const int j = t + i * 256;
        h[j] = f2bf((vals[i] - mu) * inv * gamma[j] + beta[j]);
    }
}

// ---------------------------------------------------------------------------
// Launch — chunked over batches; footprint adapts to ws_size.
// Persistent: 4 bf16 weight buffers (4.72 MB).
//
// Per-chunk layout with lifetime overlays (per-batch bytes in parens):
//   R1: xABb  bf16 [2Cb][1024][768]  == ACC f32 [Cb][1024][768]   (4*perB)
//       (xABb dead after V-GEMM; ACC first written by PV-A, mode 0, full)
//   R2: Sf    f32  [Cb][1024][1024]; xCb bf16 [Cb][1024][768] at its start
//       (xCb dead after Q-GEMM; Sf first written by score-A)     (4*perP)
//   Qb  bf16 [Cb][1024][768]  (reused as h after score-B)        (2*perB)
//   Kb  bf16 [2Cb][1024][768] (K_A then K_B halves)              (4*perB)
//   Vtb bf16 [2Cb][768][1024] (V_A^T then V_B^T halves)          (4*perB)
// Total 14*perB + 4*perP = 14.50 MB/batch (was 16.78) -> chunking never
// regresses vs the previous layout.
//
// Dispatch merges: xA/xB stacked so K_A|K_B is ONE M=2*Cb*1024 GEMM (and same
// for V) -> 3 blocks/CU co-residency instead of 1.5, half the launch tails.
// ---------------------------------------------------------------------------
extern "C" void kernel_launch(void* const* d_in, const int* in_sizes, int n_in,
                              void* d_out, int out_size, void* d_ws, size_t ws_size,
                              hipStream_t stream)
{
    const float* xA    = (const float*)d_in[0];
    const float* xB    = (const float*)d_in[1];
    const float* xC    = (const float*)d_in[2];
    const float* Wq    = (const float*)d_in[3];
    const float* bq    = (const float*)d_in[4];
    const float* Wk    = (const float*)d_in[5];
    const float* bk    = (const float*)d_in[6];
    const float* Wv    = (const float*)d_in[7];
    const float* bv    = (const float*)d_in[8];
    const float* gamma = (const float*)d_in[9];
    const float* beta  = (const float*)d_in[10];
    const float* Wfc   = (const float*)d_in[11];
    const float* bfc   = (const float*)d_in[12];
    float* out = (float*)d_out;

    const long long eW   = (long long)DIMV * DIMV;   // 589,824
    const long long perB = (long long)SEQ * DIMV;    // 786,432
    const long long perP = (long long)SEQ * SEQ;     // 1,048,576

    const long long wBytes        = 4 * eW * 2;                  // 4.72 MB
    const long long perBatchBytes = 14 * perB + 4 * perP;        // 15,204,352

    long long Cmax = ((long long)ws_size - wBytes) / perBatchBytes;
    if (Cmax > BATCH) Cmax = BATCH;
    if (Cmax < 1)     Cmax = 1;
    const int nChunks = (int)((BATCH + Cmax - 1) / Cmax);
    const int CbStd   = (BATCH + nChunks - 1) / nChunks;   // balanced chunks

    // persistent weight region
    char* cur = (char*)d_ws;
    ushort_t* Wqb  = (ushort_t*)cur; cur += eW * 2;
    ushort_t* Wkb  = (ushort_t*)cur; cur += eW * 2;
    ushort_t* Wvb  = (ushort_t*)cur; cur += eW * 2;
    ushort_t* Wfcb = (ushort_t*)cur; cur += eW * 2;
    char* chunkBase = cur;

    const float scale = 0.03608439182435161f;  // 1/sqrt(768)

    // 0) convert weights to bf16 (once)
    f32_to_bf16<<<(int)(eW / 1024), 256, 0, stream>>>(Wq,  Wqb);
    f32_to_bf16<<<(int)(eW / 1024), 256, 0, stream>>>(Wk,  Wkb);
    f32_to_bf16<<<(int)(eW / 1024), 256, 0, stream>>>(Wv,  Wvb);
    f32_to_bf16<<<(int)(eW / 1024), 256, 0, stream>>>(Wfc, Wfcb);

    for (int b0 = 0; b0 < BATCH; b0 += CbStd) {
        const int Cb = (b0 + CbStd <= BATCH) ? CbStd : (BATCH - b0);
        const long long off = (long long)b0 * perB;

        // chunk workspace layout (see header comment for overlays)
        char* p = chunkBase;
        ushort_t* xABb = (ushort_t*)p;
        float*    ACC  = (float*)p;    p += (long long)Cb * 4 * perB;   // R1
        float*    Sf   = (float*)p;
        ushort_t* xCb  = (ushort_t*)p; p += (long long)Cb * 4 * perP;   // R2
        ushort_t* Qb   = (ushort_t*)p; p += (long long)Cb * 2 * perB;
        ushort_t* Kb   = (ushort_t*)p; p += (long long)Cb * 4 * perB;
        ushort_t* Vtb  = (ushort_t*)p; p += (long long)Cb * 4 * perB;

        dim3 gq (DIMV / 128, Cb * (SEQ / 128), 1);        // M = Cb*1024
        dim3 gkv(DIMV / 128, 2 * Cb * (SEQ / 128), 1);    // M = 2*Cb*1024
        dim3 gsc(SEQ / 128, SEQ / 128, Cb);
        dim3 gpv(DIMV / 128, SEQ / 128, Cb);
        const int gcv = (int)((long long)Cb * perB / 1024);

        // 1) projections: Q from xC; K_A|K_B and V_A|V_B as single stacked GEMMs
        f32_to_bf16<<<gcv, 256, 0, stream>>>(xC + off, xCb);
        gemm_bf16_nt<<<gq, 256, 0, stream>>>(xCb, Wqb, bq, Qb,
            DIMV, DIMV, DIMV, DIMV, 1.f, 1, 0, 0, 0);
        f32_to_bf16<<<gcv, 256, 0, stream>>>(xA + off, xABb);
        f32_to_bf16<<<gcv, 256, 0, stream>>>(xB + off, xABb + (long long)Cb * perB);
        gemm_bf16_nt<<<gkv, 256, 0, stream>>>(xABb, Wkb, bk, Kb,
            DIMV, DIMV, DIMV, DIMV, 1.f, 1, 0, 0, 0);
        gemm_bf16_nt<<<gkv, 256, 0, stream>>>(xABb, Wvb, bv, Vtb,
            DIMV, DIMV, DIMV, DIMV, 1.f, 2, 0, 0, 0);

        // 2) branch A: scores -> softmax(in-place) -> PV (write ACC)
        gemm_bf16_nt<<<gsc, 256, 0, stream>>>(Qb, Kb, nullptr, Sf,
            DIMV, DIMV, DIMV, SEQ, scale, 0, perB, perB, perP);
        softmax_inplace<<<Cb * SEQ, 256, 0, stream>>>(Sf);
        gemm_bf16_nt<<<gpv, 256, 0, stream>>>((const ushort_t*)Sf, Vtb, nullptr, ACC,
            SEQ, 2 * SEQ, SEQ, DIMV, 1.f, 0, 2 * perP, perB, perB);

        // 3) branch B: scores -> softmax(in-place) -> PV (accumulate into ACC)
        gemm_bf16_nt<<<gsc, 256, 0, stream>>>(Qb, Kb + (long long)Cb * perB, nullptr, Sf,
            DIMV, DIMV, DIMV, SEQ, scale, 0, perB, perB, perP);
        softmax_inplace<<<Cb * SEQ, 256, 0, stream>>>(Sf);
        gemm_bf16_nt<<<gpv, 256, 0, stream>>>((const ushort_t*)Sf, Vtb + (long long)Cb * perB, nullptr, ACC,
            SEQ, 2 * SEQ, SEQ, DIMV, 1.f, 3, 2 * perP, perB, perB);

        // 4) h = LN(ACC + xC) -> bf16, into Qb (Q is dead now)
        add_layernorm<<<Cb * SEQ, 256, 0, stream>>>(ACC, xC + off, gamma, beta, Qb);

        // 5) out = h @ Wfc^T + bfc (f32 out)
        gemm_bf16_nt<<<gq, 256, 0, stream>>>(Qb, Wfcb, bfc, out + off,
            DIMV, DIMV, DIMV, DIMV, 1.f, 0, 0, 0, 0);
    }
}

// Round 2
// 714.252 us; speedup vs baseline: 1.3366x; 1.0456x over previous
//
#include <hip/hip_runtime.h>

#define DIMV 768
#define BATCH 16
#define SEQ 1024
#define LN_EPS 1e-5f

typedef __attribute__((ext_vector_type(8))) short bf16x8;   // 8 bf16 = 4 VGPRs
typedef __attribute__((ext_vector_type(4))) float f32x4;
typedef unsigned short ushort_t;

__device__ __forceinline__ unsigned short f2bf(float f) {
    unsigned u = __float_as_uint(f);
    u = (u + 0x7FFFu + ((u >> 16) & 1u)) >> 16;
    return (unsigned short)u;
}

// ---------------------------------------------------------------------------
// bf16 MFMA NT GEMM, ring-3 LDS pipeline: C[m,n] = scale*sum_k A[m,k]*B[n,k]+bias
// A: bf16 row-major [M, lda]; B: bf16 row-major [N, ldb] (B^T input).
// 128x128 tile, BK=32, 256 threads = 4 waves (2x2), 4x4 MFMA frags/wave.
// K-loop: depth-1 global_load_lds prefetch, ONE raw s_barrier + s_waitcnt
// vmcnt(4) per iter (tile k+1 loads stay in flight across the barrier).
// Ring-3 safety: slot written at iter k was last read at iter k-2; those reads
// precede barrier(k-1), which precedes iter-k issue. Last iter issues a dummy
// wrap prefetch so the vmcnt count stays uniform.
//
// XCD swizzles (hardware round-robins linear block id over 8 XCDs):
//  - Z>1 (attention, per-batch): remap so XCD == batch (mod 8); one batch's
//    working set (<=3.5 MB) lives in one XCD's 4 MB L2.  [round 0: worked]
//  - Z==1 (projections): chunked transform nl=(lid%8)*(nwg/8)+lid/8 so each
//    XCD owns a contiguous y-range; all x-blocks sharing an A-panel run on
//    ONE XCD -> panel fetched once (was 6 XCDs -> FETCH 3.2x compulsory).
//
// mode: 0 = f32 out; 1 = bf16 out; 2 = bf16 out transposed per-(local)batch
//       (dst[b][n][s], b = m>>10, s = m&1023); 3 = f32 accumulate (C += val);
//       4 = fused KV: n<768 -> mode-1 write to Cout (bias), n>=768 -> mode-2
//           transposed write to Cout2 (bias2, col n-768).
// ---------------------------------------------------------------------------
__global__ __launch_bounds__(256) void gemm_bf16_nt(
    const ushort_t* __restrict__ A, const ushort_t* __restrict__ B,
    const float* __restrict__ bias, const float* __restrict__ bias2,
    void* __restrict__ Cout, void* __restrict__ Cout2,
    int K, int lda, int ldb, int ldc, float scale, int mode,
    long long sAz, long long sBz, long long sCz)
{
    int bx = blockIdx.x, by = blockIdx.y, bz = blockIdx.z;
    {
        const unsigned Z  = gridDim.z;
        const unsigned nx = gridDim.x, ny = gridDim.y;
        if (Z > 1) {
            const unsigned nxy = nx * ny;
            const unsigned lid = ((unsigned)bz * ny + (unsigned)by) * nx + (unsigned)bx;
            unsigned r;
            if ((Z & 7u) == 0u) {           // XCD c runs batch c, then c+8, ...
                const unsigned c  = lid & 7u;
                const unsigned rp = lid >> 3;
                bz = (int)(c + 8u * (rp / nxy));
                r  = rp % nxy;
            } else {                        // generic bijective fallback
                bz = (int)(lid % Z);
                r  = lid / Z;
            }
            bx = (int)(r % nx);
            by = (int)(r / nx);
        } else {
            const unsigned nwg = nx * ny;
            if ((nwg & 7u) == 0u) {         // chunked: XCD c owns contiguous y-range
                const unsigned lid = (unsigned)by * nx + (unsigned)bx;
                const unsigned nl  = (lid & 7u) * (nwg >> 3) + (lid >> 3);
                bx = (int)(nl % nx);
                by = (int)(nl / nx);
            }
        }
    }

    A += (long long)bz * sAz;
    B += (long long)bz * sBz;
    float*    Cf  = (float*)Cout    + ((mode == 0 || mode == 3) ? (long long)bz * sCz : 0);
    ushort_t* Ch  = (ushort_t*)Cout + ((mode == 1 || mode == 2) ? (long long)bz * sCz : 0);
    ushort_t* Ch2 = (ushort_t*)Cout2;

    __shared__ ushort_t As[3][128 * 32];   // 3 x 8 KB
    __shared__ ushort_t Bs[3][128 * 32];   // 3 x 8 KB  (48 KB total)

    const int t    = threadIdx.x;       // 0..255
    const int wave = t >> 6;
    const int lane = t & 63;
    const int quad = lane >> 4;         // 0..3
    const int lr   = lane & 15;         // 0..15
    const int wy   = wave >> 1;         // 0/1: m-half
    const int wx   = wave & 1;          // 0/1: n-half

    const int m0 = by * 128;
    const int n0 = bx * 128;

    const ushort_t* Abase = A + (long long)m0 * lda;
    const ushort_t* Bbase = B + (long long)n0 * ldb;

    auto issue = [&](int k0, int slot) {
        #pragma unroll
        for (int i = 0; i < 2; ++i) {
            const int idx = t + 256 * i;          // 0..511: 128 rows x 4 chunks
            const int r   = idx >> 2;
            const int c   = (idx & 3) * 8;        // bf16 offset (16B chunks)
            __builtin_amdgcn_global_load_lds(
                (const __attribute__((address_space(1))) unsigned int*)(Abase + (long long)r * lda + k0 + c),
                (__attribute__((address_space(3))) unsigned int*)&As[slot][idx * 8], 16, 0, 0);
            __builtin_amdgcn_global_load_lds(
                (const __attribute__((address_space(1))) unsigned int*)(Bbase + (long long)r * ldb + k0 + c),
                (__attribute__((address_space(3))) unsigned int*)&Bs[slot][idx * 8], 16, 0, 0);
        }
    };

    f32x4 acc[4][4] = {};

    const int NK = K >> 5;
    issue(0, 0);
    int cur = 0, nxt = 1;
    for (int ki = 0; ki < NK; ++ki) {
        const int kn = (ki + 1 < NK) ? (ki + 1) << 5 : 0;  // dummy wrap on last
        issue(kn, nxt);
        asm volatile("s_waitcnt vmcnt(4)" ::: "memory");   // tile-k loads done
        asm volatile("s_barrier" ::: "memory");            // no vmcnt(0) drain

        const ushort_t* as = &As[cur][0];
        const ushort_t* bs = &Bs[cur][0];
        bf16x8 af[4], bfr[4];
        #pragma unroll
        for (int i = 0; i < 4; ++i) {
            const int row = wy * 64 + i * 16 + lr;      // A[m][k]
            af[i] = *(const bf16x8*)&as[row * 32 + quad * 8];
        }
        #pragma unroll
        for (int j = 0; j < 4; ++j) {
            const int row = wx * 64 + j * 16 + lr;      // B^T[n][k]
            bfr[j] = *(const bf16x8*)&bs[row * 32 + quad * 8];
        }
        #pragma unroll
        for (int i = 0; i < 4; ++i)
            #pragma unroll
            for (int j = 0; j < 4; ++j)
                acc[i][j] = __builtin_amdgcn_mfma_f32_16x16x32_bf16(
                    af[i], bfr[j], acc[i][j], 0, 0, 0);

        cur = nxt;
        nxt = (nxt == 2) ? 0 : nxt + 1;
    }

    // epilogue: D row(m) = quad*4 + reg, col(n) = lane&15  [m89-verified]
    #pragma unroll
    for (int j = 0; j < 4; ++j) {
        const int n = n0 + wx * 64 + j * 16 + lr;
        float bv;
        if (mode == 4) bv = (n < DIMV) ? bias[n] : bias2[n - DIMV];
        else           bv = bias ? bias[n] : 0.0f;
        #pragma unroll
        for (int i = 0; i < 4; ++i) {
            #pragma unroll
            for (int r = 0; r < 4; ++r) {
                const int m = m0 + wy * 64 + i * 16 + quad * 4 + r;
                const float val = acc[i][j][r] * scale + bv;
                if (mode == 0) {
                    Cf[(long long)m * ldc + n] = val;
                } else if (mode == 3) {
                    Cf[(long long)m * ldc + n] += val;
                } else if (mode == 1) {
                    Ch[(long long)m * ldc + n] = f2bf(val);
                } else if (mode == 2) {
                    const int b = m >> 10, s = m & 1023;
                    Ch[(long long)b * (DIMV * SEQ) + (long long)n * SEQ + s] = f2bf(val);
                } else {                      // mode 4: fused KV
                    if (n < DIMV) {           // K half (block-uniform branch)
                        Ch[(long long)m * ldc + n] = f2bf(val);
                    } else {                  // V half, transposed
                        const int b = m >> 10, s = m & 1023;
                        Ch2[(long long)b * (DIMV * SEQ) + (long long)(n - DIMV) * SEQ + s] = f2bf(val);
                    }
                }
            }
        }
    }
}

// ---------------------------------------------------------------------------
// f32 -> bf16 conversion, 4 elems/thread, count divisible by 1024
// ---------------------------------------------------------------------------
__global__ __launch_bounds__(256) void f32_to_bf16(
    const float* __restrict__ in, ushort_t* __restrict__ out)
{
    const long long i = ((long long)blockIdx.x * 256 + threadIdx.x) * 4;
    float4 v = *reinterpret_cast<const float4*>(in + i);
    ushort4 o;
    o.x = f2bf(v.x); o.y = f2bf(v.y); o.z = f2bf(v.z); o.w = f2bf(v.w);
    *reinterpret_cast<ushort4*>(out + i) = o;
}

// ---------------------------------------------------------------------------
// In-place row softmax: 1024 f32 logits -> bf16 probs written over the row
// start (row becomes 1024 bf16 + 2048B dead). All reads complete before the
// first __syncthreads, so the overlapping writes after the last barrier are
// race-free. One 256-thread block per row.
// ---------------------------------------------------------------------------
__global__ __launch_bounds__(256) void softmax_inplace(float* __restrict__ S)
{
    float* s = S + (long long)blockIdx.x * SEQ;
    const int t = threadIdx.x;
    __shared__ float red[256];

    float4 v = *reinterpret_cast<const float4*>(&s[t * 4]);
    float mx = fmaxf(fmaxf(v.x, v.y), fmaxf(v.z, v.w));
    red[t] = mx;
    __syncthreads();
    for (int st = 128; st > 0; st >>= 1) {
        if (t < st) red[t] = fmaxf(red[t], red[t + st]);
        __syncthreads();
    }
    mx = red[0];
    __syncthreads();

    v.x = __expf(v.x - mx); v.y = __expf(v.y - mx);
    v.z = __expf(v.z - mx); v.w = __expf(v.w - mx);
    red[t] = v.x + v.y + v.z + v.w;
    __syncthreads();
    for (int st = 128; st > 0; st >>= 1) {
        if (t < st) red[t] += red[t + st];
        __syncthreads();
    }
    const float inv = 1.0f / red[0];

    ushort4 o;
    o.x = f2bf(v.x * inv); o.y = f2bf(v.y * inv);
    o.z = f2bf(v.z * inv); o.w = f2bf(v.w * inv);
    *reinterpret_cast<ushort4*>((ushort_t*)s + t * 4) = o;
}

// ---------------------------------------------------------------------------
// h = LayerNorm(ACC + xC) * gamma + beta -> bf16. One block per row (768).
// ---------------------------------------------------------------------------
__global__ __launch_bounds__(256) void add_layernorm(
    const float* __restrict__ ACC, const float* __restrict__ xC,
    const float* __restrict__ gamma, const float* __restrict__ beta,
    ushort_t* __restrict__ H)
{
    const long long row = blockIdx.x;
    const float* a = ACC + row * DIMV;
    const float* x = xC  + row * DIMV;
    ushort_t*    h = H   + row * DIMV;
    const int t = threadIdx.x;

    __shared__ float r1[256];
    __shared__ float r2[256];

    float vals[3];
    float s = 0.f, ss = 0.f;
    #pragma unroll
    for (int i = 0; i < 3; ++i) {
        const int j = t + i * 256;
        float v = a[j] + x[j];
        vals[i] = v;
        s += v; ss += v * v;
    }
    r1[t] = s; r2[t] = ss;
    __syncthreads();
    for (int st = 128; st > 0; st >>= 1) {
        if (t < st) { r1[t] += r1[t + st]; r2[t] += r2[t + st]; }
        __syncthreads();
    }
    const float mu  = r1[0] * (1.0f / DIMV);
    const float var = r2[0] * (1.0f / DIMV) - mu * mu;
    const float inv = rsqrtf(var + LN_EPS);

    #pragma unroll
    for (int i = 0; i < 3; ++i) {
        const int j = t + i * 256;
        h[j] = f2bf((vals[i] - mu) * inv * gamma[j] + beta[j]);
    }
}

// ---------------------------------------------------------------------------
// Launch — chunked over batches; footprint adapts to ws_size.
// Persistent: bf16 weights Wqb | Wkvb (=[Wk;Wv], 1536x768) | Wfcb (4.72 MB).
//
// Per-chunk layout with lifetime overlays (per-batch bytes in parens):
//   R1: xABb  bf16 [2Cb][1024][768]  == ACC f32 [Cb][1024][768]   (4*perB)
//       (xABb dead after fused-KV GEMM; ACC first written by PV-A)
//   R2: Sf    f32  [Cb][1024][1024]; xCb bf16 [Cb][1024][768] at its start
//       (xCb dead after Q-GEMM; Sf first written by score-A)     (4*perP)
//   Qb  bf16 [Cb][1024][768]  (reused as h after score-B)        (2*perB)
//   Kb  bf16 [2Cb][1024][768] (K_A then K_B halves)              (4*perB)
//   Vtb bf16 [2Cb][768][1024] (V_A^T then V_B^T halves)          (4*perB)
// Total 14*perB + 4*perP = 14.50 MB/batch.
//
// Dispatch merges: xA/xB stacked AND K/V weights stacked -> ONE projection
// GEMM (M=2*Cb*1024, N=1536) produces K_A|K_B and V_A^T|V_B^T.
// ---------------------------------------------------------------------------
extern "C" void kernel_launch(void* const* d_in, const int* in_sizes, int n_in,
                              void* d_out, int out_size, void* d_ws, size_t ws_size,
                              hipStream_t stream)
{
    const float* xA    = (const float*)d_in[0];
    const float* xB    = (const float*)d_in[1];
    const float* xC    = (const float*)d_in[2];
    const float* Wq    = (const float*)d_in[3];
    const float* bq    = (const float*)d_in[4];
    const float* Wk    = (const float*)d_in[5];
    const float* bk    = (const float*)d_in[6];
    const float* Wv    = (const float*)d_in[7];
    const float* bv    = (const float*)d_in[8];
    const float* gamma = (const float*)d_in[9];
    const float* beta  = (const float*)d_in[10];
    const float* Wfc   = (const float*)d_in[11];
    const float* bfc   = (const float*)d_in[12];
    float* out = (float*)d_out;

    const long long eW   = (long long)DIMV * DIMV;   // 589,824
    const long long perB = (long long)SEQ * DIMV;    // 786,432
    const long long perP = (long long)SEQ * SEQ;     // 1,048,576

    const long long wBytes        = 4 * eW * 2;                  // 4.72 MB
    const long long perBatchBytes = 14 * perB + 4 * perP;        // 15,204,352

    long long Cmax = ((long long)ws_size - wBytes) / perBatchBytes;
    if (Cmax > BATCH) Cmax = BATCH;
    if (Cmax < 1)     Cmax = 1;
    const int nChunks = (int)((BATCH + Cmax - 1) / Cmax);
    const int CbStd   = (BATCH + nChunks - 1) / nChunks;   // balanced chunks

    // persistent weight region
    char* cur = (char*)d_ws;
    ushort_t* Wqb  = (ushort_t*)cur; cur += eW * 2;
    ushort_t* Wkvb = (ushort_t*)cur; cur += 2 * eW * 2;    // [Wk; Wv] 1536x768
    ushort_t* Wfcb = (ushort_t*)cur; cur += eW * 2;
    char* chunkBase = cur;

    const float scale = 0.03608439182435161f;  // 1/sqrt(768)

    // 0) convert weights to bf16 (once)
    f32_to_bf16<<<(int)(eW / 1024), 256, 0, stream>>>(Wq,  Wqb);
    f32_to_bf16<<<(int)(eW / 1024), 256, 0, stream>>>(Wk,  Wkvb);
    f32_to_bf16<<<(int)(eW / 1024), 256, 0, stream>>>(Wv,  Wkvb + eW);
    f32_to_bf16<<<(int)(eW / 1024), 256, 0, stream>>>(Wfc, Wfcb);

    for (int b0 = 0; b0 < BATCH; b0 += CbStd) {
        const int Cb = (b0 + CbStd <= BATCH) ? CbStd : (BATCH - b0);
        const long long off = (long long)b0 * perB;

        // chunk workspace layout (see header comment for overlays)
        char* p = chunkBase;
        ushort_t* xABb = (ushort_t*)p;
        float*    ACC  = (float*)p;    p += (long long)Cb * 4 * perB;   // R1
        float*    Sf   = (float*)p;
        ushort_t* xCb  = (ushort_t*)p; p += (long long)Cb * 4 * perP;   // R2
        ushort_t* Qb   = (ushort_t*)p; p += (long long)Cb * 2 * perB;
        ushort_t* Kb   = (ushort_t*)p; p += (long long)Cb * 4 * perB;
        ushort_t* Vtb  = (ushort_t*)p; p += (long long)Cb * 4 * perB;

        dim3 gq  (DIMV / 128, Cb * (SEQ / 128), 1);           // M = Cb*1024
        dim3 gkv (2 * DIMV / 128, 2 * Cb * (SEQ / 128), 1);   // M = 2*Cb*1024, N = 1536
        dim3 gsc (SEQ / 128, SEQ / 128, Cb);
        dim3 gpv (DIMV / 128, SEQ / 128, Cb);
        const int gcv = (int)((long long)Cb * perB / 1024);

        // 1) projections: Q from xC; fused K|V GEMM from stacked xA|xB
        f32_to_bf16<<<gcv, 256, 0, stream>>>(xC + off, xCb);
        gemm_bf16_nt<<<gq, 256, 0, stream>>>(xCb, Wqb, bq, nullptr, Qb, nullptr,
            DIMV, DIMV, DIMV, DIMV, 1.f, 1, 0, 0, 0);
        f32_to_bf16<<<gcv, 256, 0, stream>>>(xA + off, xABb);
        f32_to_bf16<<<gcv, 256, 0, stream>>>(xB + off, xABb + (long long)Cb * perB);
        gemm_bf16_nt<<<gkv, 256, 0, stream>>>(xABb, Wkvb, bk, bv, Kb, Vtb,
            DIMV, DIMV, DIMV, DIMV, 1.f, 4, 0, 0, 0);

        // 2) branch A: scores -> softmax(in-place) -> PV (write ACC)
        gemm_bf16_nt<<<gsc, 256, 0, stream>>>(Qb, Kb, nullptr, nullptr, Sf, nullptr,
            DIMV, DIMV, DIMV, SEQ, scale, 0, perB, perB, perP);
        softmax_inplace<<<Cb * SEQ, 256, 0, stream>>>(Sf);
        gemm_bf16_nt<<<gpv, 256, 0, stream>>>((const ushort_t*)Sf, Vtb, nullptr, nullptr, ACC, nullptr,
            SEQ, 2 * SEQ, SEQ, DIMV, 1.f, 0, 2 * perP, perB, perB);

        // 3) branch B: scores -> softmax(in-place) -> PV (accumulate into ACC)
        gemm_bf16_nt<<<gsc, 256, 0, stream>>>(Qb, Kb + (long long)Cb * perB, nullptr, nullptr, Sf, nullptr,
            DIMV, DIMV, DIMV, SEQ, scale, 0, perB, perB, perP);
        softmax_inplace<<<Cb * SEQ, 256, 0, stream>>>(Sf);
        gemm_bf16_nt<<<gpv, 256, 0, stream>>>((const ushort_t*)Sf, Vtb + (long long)Cb * perB, nullptr, nullptr, ACC, nullptr,
            SEQ, 2 * SEQ, SEQ, DIMV, 1.f, 3, 2 * perP, perB, perB);

        // 4) h = LN(ACC + xC) -> bf16, into Qb (Q is dead now)
        add_layernorm<<<Cb * SEQ, 256, 0, stream>>>(ACC, xC + off, gamma, beta, Qb);

        // 5) out = h @ Wfc^T + bfc (f32 out)
        gemm_bf16_nt<<<gq, 256, 0, stream>>>(Qb, Wfcb, bfc, nullptr, out + off, nullptr,
            DIMV, DIMV, DIMV, DIMV, 1.f, 0, 0, 0, 0);
    }
}